// Round 2
// baseline (724.078 us; speedup 1.0000x reference)
//
#include <hip/hip_runtime.h>

// WaveNet_33036888440853: out[b] = sum_c det( mo[b][cfg[c],cfg[c]] ) * W_ci[c]
// mo = x @ W_mo^T.  B=1024, NE=NAO=NMO=128, NC=32, D=64.  All fp32.
// One block (256 thr) per batch b. mo[b] in LDS; 32 LU dets (64x64, partial
// pivoting) done 4-at-a-time (1 wave each), rows-in-lanes, columns in regs.
// Pivot row broadcast via v_readlane (uniform p) -> no LDS RAW, no DPP.

constexpr int NE  = 128;
constexpr int NAO = 128;
constexpr int D   = 64;

constexpr int MOS = 129;  // mo_ls stride: (129R+c)%32=(R+c)%32 -> ~2-way on gather
constexpr int GS  = 132;  // staging stride: mult of 4 (aligned b128)

__device__ __forceinline__ float readlane_f(float v, int lane) {
  return __int_as_float(__builtin_amdgcn_readlane(__float_as_int(v), lane));
}

__global__ __launch_bounds__(256) void wavenet_kernel(
    const float* __restrict__ x, const float* __restrict__ W_mo,
    const float* __restrict__ W_ci, const int* __restrict__ configs,
    float* __restrict__ out) {
  __shared__ float mo_ls[128 * MOS];
  __shared__ float x_ls[8 * GS];
  __shared__ float w_ls[8 * GS];
  __shared__ float partial[4];

  const int t    = threadIdx.x;
  const int b    = blockIdx.x;
  const int lane = t & 63;
  const int w    = t >> 6;

  // ---------------- Phase 1: mo_ls = x[b] @ W_mo^T (128x128) ----------------
  const int tx = t & 15, ty = t >> 4;
  const int c0 = tx * 8, r0 = ty * 8;
  const float* xb = x + (size_t)b * NE * NAO;

  float acc[8][8];
#pragma unroll
  for (int i = 0; i < 8; ++i)
#pragma unroll
    for (int j = 0; j < 8; ++j) acc[i][j] = 0.f;

  const int le = t >> 1;        // staging row 0..127
  const int lh = (t & 1) * 4;   // k-half 0 or 4

  for (int kb = 0; kb < 16; ++kb) {  // BK = 8
    const float4 xv = *reinterpret_cast<const float4*>(xb + le * NAO + kb * 8 + lh);
    const float4 wv = *reinterpret_cast<const float4*>(W_mo + le * NAO + kb * 8 + lh);
    x_ls[(lh + 0) * GS + le] = xv.x;
    x_ls[(lh + 1) * GS + le] = xv.y;
    x_ls[(lh + 2) * GS + le] = xv.z;
    x_ls[(lh + 3) * GS + le] = xv.w;
    w_ls[(lh + 0) * GS + le] = wv.x;
    w_ls[(lh + 1) * GS + le] = wv.y;
    w_ls[(lh + 2) * GS + le] = wv.z;
    w_ls[(lh + 3) * GS + le] = wv.w;
    __syncthreads();
#pragma unroll
    for (int nn = 0; nn < 8; ++nn) {
      const float4 a0 = *reinterpret_cast<const float4*>(&x_ls[nn * GS + r0]);
      const float4 a1 = *reinterpret_cast<const float4*>(&x_ls[nn * GS + r0 + 4]);
      const float4 b0 = *reinterpret_cast<const float4*>(&w_ls[nn * GS + c0]);
      const float4 b1 = *reinterpret_cast<const float4*>(&w_ls[nn * GS + c0 + 4]);
      const float av[8] = {a0.x, a0.y, a0.z, a0.w, a1.x, a1.y, a1.z, a1.w};
      const float bv[8] = {b0.x, b0.y, b0.z, b0.w, b1.x, b1.y, b1.z, b1.w};
#pragma unroll
      for (int i = 0; i < 8; ++i)
#pragma unroll
        for (int j = 0; j < 8; ++j) acc[i][j] = fmaf(av[i], bv[j], acc[i][j]);
    }
    __syncthreads();
  }
#pragma unroll
  for (int i = 0; i < 8; ++i)
#pragma unroll
    for (int j = 0; j < 8; ++j) mo_ls[(r0 + i) * MOS + c0 + j] = acc[i][j];
  __syncthreads();

  // ---------------- Phase 2: 8 LUs per wave, no block barriers --------------
  float waveacc = 0.f;

#pragma unroll 1
  for (int cc = 0; cc < 8; ++cc) {
    const int c = w * 8 + cc;
    const int cjv     = configs[c * D + lane];  // lane's row config index
    const int rowbase = cjv * MOS;

    float a[64];
#pragma unroll
    for (int j = 0; j < 64; ++j) {
      const int cj = __builtin_amdgcn_readlane(cjv, j);  // column config index
      a[j] = mo_ls[rowbase + cj];
    }

    int myslot = lane;   // virtual row-slot (tracks permutation for sign)
    float det  = 1.f;

#pragma unroll
    for (int k = 0; k < 64; ++k) {
      const float ak  = a[k];
      const bool  act = (myslot >= k);
      float v = act ? fabsf(ak) : -1.f;
#pragma unroll
      for (int off = 32; off; off >>= 1) v = fmaxf(v, __shfl_xor(v, off));

      const unsigned long long bal = __ballot(act && (fabsf(ak) == v));
      const int p = (int)__builtin_ctzll(bal);

      const float pv = readlane_f(ak, p);
      float invp = 0.f;
      if (v > 0.f) {
        invp = __builtin_amdgcn_rcpf(pv);
        invp = invp * (2.f - pv * invp);  // one NR step
        det *= pv;
      } else {
        det = 0.f;  // singular: freeze (invp=0 -> no-op updates)
      }

      // sign via slot swap (LAPACK p!=k rule in slot space)
      const int sp = __builtin_amdgcn_readlane(myslot, p);
      if (sp != k) det = -det;
      myslot = (lane == p) ? k : ((myslot == k) ? sp : myslot);

      const float m = (myslot > k) ? ak * invp : 0.f;  // pivot & retired rows: no-op
#pragma unroll
      for (int j = k + 1; j < 64; ++j)
        a[j] = fmaf(-m, readlane_f(a[j], p), a[j]);
    }
    waveacc += det * W_ci[c];
  }

  if (lane == 0) partial[w] = waveacc;
  __syncthreads();
  if (t == 0) out[b] = partial[0] + partial[1] + partial[2] + partial[3];
}

extern "C" void kernel_launch(void* const* d_in, const int* in_sizes, int n_in,
                              void* d_out, int out_size, void* d_ws, size_t ws_size,
                              hipStream_t stream) {
  (void)in_sizes; (void)n_in; (void)d_ws; (void)ws_size; (void)out_size;
  const float* x       = (const float*)d_in[0];
  const float* W_mo    = (const float*)d_in[1];
  const float* W_ci    = (const float*)d_in[2];
  const int*   configs = (const int*)d_in[3];
  float*       out     = (float*)d_out;
  hipLaunchKernelGGL(wavenet_kernel, dim3(1024), dim3(256), 0, stream,
                     x, W_mo, W_ci, configs, out);
}

// Round 3
// 535.803 us; speedup vs baseline: 1.3514x; 1.3514x over previous
//
#include <hip/hip_runtime.h>

// WaveNet_33036888440853: out[b] = sum_c det( mo[b][cfg[c],cfg[c]] ) * W_ci[c]
// mo = x @ W_mo^T.  B=1024, NE=NAO=NMO=128, NC=32, D=64.  All fp32.
// One block (256 thr) per batch b. mo[b] in LDS; 32 LU dets (64x64) done
// 4-at-a-time (1 wave each), rows-in-lanes, columns in regs.
// Pivoting: diagonal-first THRESHOLD pivoting (tau=0.02). Full max-reduce
// only as a rare backstop -> no per-step shuffle chains in the hot path.

constexpr int NE  = 128;
constexpr int NAO = 128;
constexpr int D   = 64;

constexpr int MOS = 129;  // mo_ls stride: (129R+c)%32=(R+c)%32 -> ~2-way on gather
constexpr int GS  = 132;  // staging stride: mult of 4 (aligned b128)

constexpr float TAU = 0.02f;  // mo entries ~ N(0, 0.2^2); P(|diag|<tau) ~ 8%

__device__ __forceinline__ float readlane_f(float v, int lane) {
  return __int_as_float(__builtin_amdgcn_readlane(__float_as_int(v), lane));
}

__global__ __launch_bounds__(256) void wavenet_kernel(
    const float* __restrict__ x, const float* __restrict__ W_mo,
    const float* __restrict__ W_ci, const int* __restrict__ configs,
    float* __restrict__ out) {
  __shared__ float mo_ls[128 * MOS];
  __shared__ float x_ls[8 * GS];
  __shared__ float w_ls[8 * GS];
  __shared__ float partial[4];

  const int t    = threadIdx.x;
  const int b    = blockIdx.x;
  const int lane = t & 63;
  const int w    = t >> 6;

  // ---------------- Phase 1: mo_ls = x[b] @ W_mo^T (128x128) ----------------
  const int tx = t & 15, ty = t >> 4;
  const int c0 = tx * 8, r0 = ty * 8;
  const float* xb = x + (size_t)b * NE * NAO;

  float acc[8][8];
#pragma unroll
  for (int i = 0; i < 8; ++i)
#pragma unroll
    for (int j = 0; j < 8; ++j) acc[i][j] = 0.f;

  const int le = t >> 1;        // staging row 0..127
  const int lh = (t & 1) * 4;   // k-half 0 or 4

  for (int kb = 0; kb < 16; ++kb) {  // BK = 8
    const float4 xv = *reinterpret_cast<const float4*>(xb + le * NAO + kb * 8 + lh);
    const float4 wv = *reinterpret_cast<const float4*>(W_mo + le * NAO + kb * 8 + lh);
    x_ls[(lh + 0) * GS + le] = xv.x;
    x_ls[(lh + 1) * GS + le] = xv.y;
    x_ls[(lh + 2) * GS + le] = xv.z;
    x_ls[(lh + 3) * GS + le] = xv.w;
    w_ls[(lh + 0) * GS + le] = wv.x;
    w_ls[(lh + 1) * GS + le] = wv.y;
    w_ls[(lh + 2) * GS + le] = wv.z;
    w_ls[(lh + 3) * GS + le] = wv.w;
    __syncthreads();
#pragma unroll
    for (int nn = 0; nn < 8; ++nn) {
      const float4 a0 = *reinterpret_cast<const float4*>(&x_ls[nn * GS + r0]);
      const float4 a1 = *reinterpret_cast<const float4*>(&x_ls[nn * GS + r0 + 4]);
      const float4 b0 = *reinterpret_cast<const float4*>(&w_ls[nn * GS + c0]);
      const float4 b1 = *reinterpret_cast<const float4*>(&w_ls[nn * GS + c0 + 4]);
      const float av[8] = {a0.x, a0.y, a0.z, a0.w, a1.x, a1.y, a1.z, a1.w};
      const float bv[8] = {b0.x, b0.y, b0.z, b0.w, b1.x, b1.y, b1.z, b1.w};
#pragma unroll
      for (int i = 0; i < 8; ++i)
#pragma unroll
        for (int j = 0; j < 8; ++j) acc[i][j] = fmaf(av[i], bv[j], acc[i][j]);
    }
    __syncthreads();
  }
#pragma unroll
  for (int i = 0; i < 8; ++i)
#pragma unroll
    for (int j = 0; j < 8; ++j) mo_ls[(r0 + i) * MOS + c0 + j] = acc[i][j];
  __syncthreads();

  // ---------------- Phase 2: 8 LUs per wave, no block barriers --------------
  float waveacc = 0.f;

#pragma unroll 1
  for (int cc = 0; cc < 8; ++cc) {
    const int c = w * 8 + cc;
    const int cjv     = configs[c * D + lane];  // lane's row config index
    const int rowbase = cjv * MOS;

    float a[64];
#pragma unroll
    for (int j = 0; j < 64; ++j) {
      const int cj = __builtin_amdgcn_readlane(cjv, j);  // column config index
      a[j] = mo_ls[rowbase + cj];
    }

    int myslot = lane;   // virtual row-slot (tracks permutation for sign)
    float det  = 1.f;

#pragma unroll
    for (int k = 0; k < 64; ++k) {
      const float ak  = a[k];
      // --- pivot selection: diagonal-first threshold pivoting ---
      unsigned long long dbal = __ballot(myslot == k);
      int   p  = (int)__builtin_ctzll(dbal);
      float pv = readlane_f(ak, p);

      if (!(fabsf(pv) > TAU)) {  // wave-uniform, rare (~8%)
        const bool act = (myslot >= k);
        unsigned long long cbal = __ballot(act && (fabsf(ak) > TAU));
        if (cbal == 0ull) {      // very rare: all candidates tiny -> true max
          float v = act ? fabsf(ak) : -1.f;
#pragma unroll
          for (int off = 32; off; off >>= 1) v = fmaxf(v, __shfl_xor(v, off));
          cbal = __ballot(act && (fabsf(ak) == v));
          if (cbal == 0ull) cbal = __ballot(act);  // paranoia
        }
        p  = (int)__builtin_ctzll(cbal);
        pv = readlane_f(ak, p);
        // swap + sign (LAPACK p!=k rule in slot space)
        const int sp = __builtin_amdgcn_readlane(myslot, p);
        if (sp != k) det = -det;
        myslot = (lane == p) ? k : ((myslot == k) ? sp : myslot);
      }

      float invp;
      if (pv != 0.f) {
        invp = __builtin_amdgcn_rcpf(pv);
        invp = invp * (2.f - pv * invp);  // one NR step
        det *= pv;
      } else {
        det  = 0.f;   // singular: freeze (invp=0 -> no-op updates)
        invp = 0.f;
      }

      const float m = (myslot > k) ? ak * invp : 0.f;  // pivot & retired rows: no-op
#pragma unroll
      for (int j = k + 1; j < 64; ++j)
        a[j] = fmaf(-m, readlane_f(a[j], p), a[j]);
    }
    waveacc += det * W_ci[c];
  }

  if (lane == 0) partial[w] = waveacc;
  __syncthreads();
  if (t == 0) out[b] = partial[0] + partial[1] + partial[2] + partial[3];
}

extern "C" void kernel_launch(void* const* d_in, const int* in_sizes, int n_in,
                              void* d_out, int out_size, void* d_ws, size_t ws_size,
                              hipStream_t stream) {
  (void)in_sizes; (void)n_in; (void)d_ws; (void)ws_size; (void)out_size;
  const float* x       = (const float*)d_in[0];
  const float* W_mo    = (const float*)d_in[1];
  const float* W_ci    = (const float*)d_in[2];
  const int*   configs = (const int*)d_in[3];
  float*       out     = (float*)d_out;
  hipLaunchKernelGGL(wavenet_kernel, dim3(1024), dim3(256), 0, stream,
                     x, W_mo, W_ci, configs, out);
}